// Round 21
// baseline (580.681 us; speedup 1.0000x reference)
//
#include <hip/hip_runtime.h>

// Round 21: FUSED SAGE LAYER. R20 k_gemm<1> = 43.5us at 21% occupancy (782 blocks
// x 4 waves = 12 waves/CU grid limit) + AGGb round-trip (25.6MB) + RMW re-read.
// k_layer: 512-thr block per 64 nodes; phase1 stages old-X rows + gathers neighbors
// into LDS (half-wave x unroll, ~same per-CU MLP as k_agg); phase2 MFMA with 64-col
// wave tiles (2x TLP), LN cross-wave via LDS, residual from LDS, fused scores (l=3).
// Ping-pong X buffers kill the cross-block write/read race. CSR/pool/tail = R20.

#define H 128
#define PPG 16
#define BKSH 8
#define CH 4096
#define AP 136                 // padded LDS row stride in bf16 units (2-way conflicts only)

typedef unsigned short u16;
typedef __attribute__((ext_vector_type(8))) short bf16x8;
typedef __attribute__((ext_vector_type(4))) float f32x4;

__device__ __forceinline__ float b2f(u16 u){ return __uint_as_float(((unsigned)u) << 16); }
__device__ __forceinline__ u16 f2b(float f){
    unsigned x = __float_as_uint(f);
    unsigned r = x + 0x7fffu + ((x >> 16) & 1u);   // RNE fp32->bf16
    return (u16)(r >> 16);
}
__device__ __forceinline__ bf16x8 cvt8(const float* __restrict__ p){
    bf16x8 v;
    #pragma unroll
    for (int j = 0; j < 8; j++) v[j] = (short)f2b(p[j]);
    return v;
}

__global__ void k_split(const float* __restrict__ W, u16* __restrict__ hi, int n){
    int i = blockIdx.x * 256 + threadIdx.x;
    if (i < n) hi[i] = f2b(W[i]);
}

// ---------------- bucketed CSR build (R20) ----------------
__global__ __launch_bounds__(1024) void k_bcnt(const int* __restrict__ dst, int* __restrict__ bcnt,
                                               int E, int NBK){
    __shared__ int cnt[256];
    int tid = threadIdx.x;
    if (tid < 256) cnt[tid] = 0;
    __syncthreads();
    int e0 = blockIdx.x * CH;
    int n = min(CH, E - e0);
    for (int j = tid; j < n; j += 1024) atomicAdd(&cnt[dst[e0 + j] >> BKSH], 1);
    __syncthreads();
    if (tid < NBK && cnt[tid]) atomicAdd(&bcnt[tid], cnt[tid]);
}

__global__ void k_bscan(const int* __restrict__ bcnt, int* __restrict__ boff,
                        int* __restrict__ bcur, int* __restrict__ offs, int NBK, int N){
    if (threadIdx.x || blockIdx.x) return;
    int run = 0;
    for (int k = 0; k < NBK; k++){ boff[k] = run; bcur[k] = run; run += bcnt[k]; }
    boff[NBK] = run;
    offs[N] = run;
}

__global__ __launch_bounds__(1024) void k_bscatter(const int* __restrict__ src, const int* __restrict__ dst,
                                                   unsigned* __restrict__ ebuf, int* __restrict__ bcur,
                                                   int E, int NBK){
    __shared__ int cnt[256], pre[256], loc[256], lcur[256], base[256];
    __shared__ unsigned stage[CH];
    int tid = threadIdx.x;
    if (tid < 256){ cnt[tid] = 0; }
    __syncthreads();
    int e0 = blockIdx.x * CH;
    int n = min(CH, E - e0);
    for (int j = tid; j < n; j += 1024) atomicAdd(&cnt[dst[e0 + j] >> BKSH], 1);
    __syncthreads();
    if (tid < NBK) base[tid] = atomicAdd(&bcur[tid], cnt[tid]);
    if (tid < 256) pre[tid] = cnt[tid];
    __syncthreads();
    for (int off = 1; off < 256; off <<= 1){
        int v = (tid < 256 && tid >= off) ? pre[tid - off] : 0;
        __syncthreads();
        if (tid < 256) pre[tid] += v;
        __syncthreads();
    }
    if (tid < 256){ loc[tid] = pre[tid] - cnt[tid]; lcur[tid] = loc[tid]; }
    __syncthreads();
    for (int j = tid; j < n; j += 1024){
        int d = dst[e0 + j], s = src[e0 + j];
        int k = d >> BKSH;
        int p = atomicAdd(&lcur[k], 1);
        stage[p] = (unsigned)d | ((unsigned)s << 16);
    }
    __syncthreads();
    for (int j = tid; j < n; j += 1024){
        unsigned v = stage[j];
        int k = (v & 0xffffu) >> BKSH;
        ebuf[base[k] + (j - loc[k])] = v;
    }
}

__global__ __launch_bounds__(256) void k_bfill(const unsigned* __restrict__ ebuf, const int* __restrict__ boff,
                                               int* __restrict__ offs, int* __restrict__ csr,
                                               float* __restrict__ invdeg, int N){
    __shared__ int deg[256], pre[256], cur[256];
    int k = blockIdx.x, tid = threadIdx.x;
    int node0 = k << BKSH;
    int s0 = boff[k], s1 = boff[k + 1];
    deg[tid] = 0;
    __syncthreads();
    for (int j = s0 + tid; j < s1; j += 256) atomicAdd(&deg[ebuf[j] & 255u], 1);
    __syncthreads();
    pre[tid] = deg[tid];
    __syncthreads();
    for (int off = 1; off < 256; off <<= 1){
        int v = (tid >= off) ? pre[tid - off] : 0;
        __syncthreads();
        pre[tid] += v;
        __syncthreads();
    }
    int excl = pre[tid] - deg[tid];
    int node = node0 + tid;
    if (node < N){
        offs[node] = s0 + excl;
        invdeg[node] = 1.0f / (float)max(deg[tid], 1);
    }
    cur[tid] = s0 + excl;
    __syncthreads();
    for (int j = s0 + tid; j < s1; j += 256){
        unsigned v = ebuf[j];
        int p = atomicAdd(&cur[v & 255u], 1);
        csr[p] = (int)(v >> 16);
    }
}

__global__ void k_start(const int* __restrict__ batch, int* __restrict__ start, int N, int B){
    int n = blockIdx.x * blockDim.x + threadIdx.x;
    if (n >= N) return;
    int b = batch[n];
    int bp = (n == 0) ? -1 : batch[n - 1];
    for (int g = bp + 1; g <= b; g++) start[g] = n;
    if (n == N - 1){ for (int g = b + 1; g <= B; g++) start[g] = N; }
}

// ---------------- fused SAGE layer ----------------
template<bool FSC>
__global__ __launch_bounds__(512) void k_layer(const u16* __restrict__ Xin, u16* __restrict__ Xout,
    const u16* __restrict__ W1, const u16* __restrict__ W2,
    const float* __restrict__ bias, const float* __restrict__ lng, const float* __restrict__ lnb,
    const int* __restrict__ offs, const int* __restrict__ csr, const float* __restrict__ invdeg,
    const float* __restrict__ qk, const float* __restrict__ qkb, float* __restrict__ scores, int N)
{
    __shared__ u16 xs[64 * AP];
    __shared__ u16 ag[64 * AP];
    __shared__ float lnbuf[2][64][2];
    __shared__ float scbuf[2][64][4];
    const int tid = threadIdx.x;
    const int wv = tid >> 6;
    const int l = tid & 63;
    const int node0 = blockIdx.x * 64;

    // phase 1a: stage old X rows (coalesced)
    for (int c = tid; c < 1024; c += 512){
        int row = c >> 4, off = (c & 15) * 8;
        bf16x8 v = {0,0,0,0,0,0,0,0};
        if (node0 + row < N) v = *(const bf16x8*)(Xin + (size_t)(node0 + row) * H + off);
        *(bf16x8*)(xs + row * AP + off) = v;
    }
    // phase 1b: gather neighbors (wave per 8 nodes, half-wave x unroll)
    {
        int half = l >> 5, sl = l & 31;
        for (int j = 0; j < 8; j++){
            int rl = wv * 8 + j;
            int node = node0 + rl;
            if (node >= N) break;
            int o0 = offs[node], o1 = offs[node + 1];
            float a0 = 0.f, a1 = 0.f, a2 = 0.f, a3 = 0.f;
            int i = o0 + half;
            for (; i + 2 < o1; i += 4){
                int s0 = csr[i], s1 = csr[i + 2];
                uint2 u0 = *(const uint2*)(Xin + (size_t)s0 * H + 4 * sl);
                uint2 u1 = *(const uint2*)(Xin + (size_t)s1 * H + 4 * sl);
                a0 += b2f((u16)(u0.x & 0xffffu)) + b2f((u16)(u1.x & 0xffffu));
                a1 += b2f((u16)(u0.x >> 16))     + b2f((u16)(u1.x >> 16));
                a2 += b2f((u16)(u0.y & 0xffffu)) + b2f((u16)(u1.y & 0xffffu));
                a3 += b2f((u16)(u0.y >> 16))     + b2f((u16)(u1.y >> 16));
            }
            for (; i < o1; i += 2){
                int s = csr[i];
                uint2 u = *(const uint2*)(Xin + (size_t)s * H + 4 * sl);
                a0 += b2f((u16)(u.x & 0xffffu));
                a1 += b2f((u16)(u.x >> 16));
                a2 += b2f((u16)(u.y & 0xffffu));
                a3 += b2f((u16)(u.y >> 16));
            }
            a0 += __shfl_xor(a0, 32, 64);
            a1 += __shfl_xor(a1, 32, 64);
            a2 += __shfl_xor(a2, 32, 64);
            a3 += __shfl_xor(a3, 32, 64);
            if (half == 0){
                float id = invdeg[node];
                ushort4 o;
                o.x = f2b(a0 * id); o.y = f2b(a1 * id); o.z = f2b(a2 * id); o.w = f2b(a3 * id);
                *(ushort4*)(ag + rl * AP + 4 * sl) = o;
            }
        }
    }
    __syncthreads();

    // phase 2: MFMA, wave tile = 16 rows x 64 cols
    const int q = l >> 4, t = l & 15;
    const int r0 = (wv & 3) * 16;
    const int chh = wv >> 2;            // column half
    const int c0 = chh * 64;

    bf16x8 a1[4], a2[4];
    #pragma unroll
    for (int kk = 0; kk < 4; kk++){
        a1[kk] = *(const bf16x8*)(ag + (r0 + t) * AP + q * 8 + kk * 32);
        a2[kk] = *(const bf16x8*)(xs + (r0 + t) * AP + q * 8 + kk * 32);
    }
    f32x4 acc[4];
    #pragma unroll
    for (int nt = 0; nt < 4; nt++){
        f32x4 c = {0.f, 0.f, 0.f, 0.f};
        const size_t wof = (size_t)(c0 + nt * 16 + t) * H + q * 8;
        #pragma unroll
        for (int kk = 0; kk < 4; kk++)
            c = __builtin_amdgcn_mfma_f32_16x16x32_bf16(a1[kk], *(const bf16x8*)(W1 + wof + kk * 32), c, 0, 0, 0);
        #pragma unroll
        for (int kk = 0; kk < 4; kk++)
            c = __builtin_amdgcn_mfma_f32_16x16x32_bf16(a2[kk], *(const bf16x8*)(W2 + wof + kk * 32), c, 0, 0, 0);
        acc[nt] = c;
    }
    float bv[4], gv[4], lbv[4], qkv[4][4];
    #pragma unroll
    for (int nt = 0; nt < 4; nt++){
        int col = c0 + nt * 16 + t;
        bv[nt] = bias[col]; gv[nt] = lng[col]; lbv[nt] = lnb[col];
        if (FSC){
            #pragma unroll
            for (int h = 0; h < 4; h++) qkv[h][nt] = qk[h * H + col];
        }
    }
    float hv[4][4];
    #pragma unroll
    for (int r = 0; r < 4; r++){
        float s = 0.f, s2 = 0.f;
        #pragma unroll
        for (int nt = 0; nt < 4; nt++){
            float v = acc[nt][r] + bv[nt];
            hv[r][nt] = v; s += v; s2 += v * v;
        }
        #pragma unroll
        for (int m = 1; m < 16; m <<= 1){ s += __shfl_xor(s, m, 64); s2 += __shfl_xor(s2, m, 64); }
        if (t == 0){
            int rl = r0 + q * 4 + r;
            lnbuf[chh][rl][0] = s;
            lnbuf[chh][rl][1] = s2;
        }
    }
    __syncthreads();
    #pragma unroll
    for (int r = 0; r < 4; r++){
        int rl = r0 + q * 4 + r;
        int row = node0 + rl;
        float s  = lnbuf[0][rl][0] + lnbuf[1][rl][0];
        float s2 = lnbuf[0][rl][1] + lnbuf[1][rl][1];
        float mean = s * (1.f / H);
        float var  = s2 * (1.f / H) - mean * mean;
        float rstd = rsqrtf(var + 1e-5f);
        if (row < N){
            float sc[4] = {0.f, 0.f, 0.f, 0.f};
            #pragma unroll
            for (int nt = 0; nt < 4; nt++){
                int col = c0 + nt * 16 + t;
                float v = (hv[r][nt] - mean) * rstd * gv[nt] + lbv[nt];
                float nv = fmaxf(v, 0.f) + b2f(xs[rl * AP + col]);
                Xout[(size_t)row * H + col] = f2b(nv);
                if (FSC){
                    #pragma unroll
                    for (int h = 0; h < 4; h++) sc[h] += nv * qkv[h][nt];
                }
            }
            if (FSC){
                #pragma unroll
                for (int m = 1; m < 16; m <<= 1){
                    #pragma unroll
                    for (int h = 0; h < 4; h++) sc[h] += __shfl_xor(sc[h], m, 64);
                }
                if (t == 0){
                    #pragma unroll
                    for (int h = 0; h < 4; h++) scbuf[chh][rl][h] = sc[h];
                }
            }
        }
    }
    if (FSC){
        __syncthreads();
        if (tid < 256){
            int rl = tid >> 2, h = tid & 3;
            int row = node0 + rl;
            if (row < N) scores[row * 4 + h] = scbuf[0][rl][h] + scbuf[1][rl][h] + qkb[h];
        }
    }
}

// ---------------- projection GEMMs (in-proj / V), R20 structure ----------------
// MODE 0: OUTb = bf16(relu(NF_fp32 @ W^T + bias)) ; MODE 2: OUTb = bf16(A1b @ W^T + bias)
template<int MODE>
__global__ __launch_bounds__(256) void k_proj(const void* __restrict__ A1v,
                                              const u16* __restrict__ W1, const float* __restrict__ bias,
                                              u16* __restrict__ OUTb, int nrows){
    const int wave = threadIdx.x >> 6;
    const int l = threadIdx.x & 63;
    const int q = l >> 4;
    const int t = l & 15;
    const int row0 = blockIdx.x * 64 + wave * 16;
    const int rowA = min(row0 + t, nrows - 1);

    bf16x8 a1[4];
    if (MODE == 0){
        const float* p = (const float*)A1v + (size_t)rowA * H + q * 8;
        #pragma unroll
        for (int kk = 0; kk < 4; kk++) a1[kk] = cvt8(p + kk * 32);
    } else {
        const u16* p = (const u16*)A1v + (size_t)rowA * H + q * 8;
        #pragma unroll
        for (int kk = 0; kk < 4; kk++) a1[kk] = *(const bf16x8*)(p + kk * 32);
    }
    f32x4 acc[8];
    #pragma unroll
    for (int nt = 0; nt < 8; nt++){
        f32x4 c = {0.f, 0.f, 0.f, 0.f};
        const size_t wof = (size_t)(nt * 16 + t) * H + q * 8;
        #pragma unroll
        for (int kk = 0; kk < 4; kk++)
            c = __builtin_amdgcn_mfma_f32_16x16x32_bf16(a1[kk], *(const bf16x8*)(W1 + wof + kk * 32), c, 0, 0, 0);
        acc[nt] = c;
    }
    float bv[8];
    #pragma unroll
    for (int nt = 0; nt < 8; nt++) bv[nt] = bias[nt * 16 + t];
    #pragma unroll
    for (int r = 0; r < 4; r++){
        int row = row0 + q * 4 + r;
        if (row < nrows){
            #pragma unroll
            for (int nt = 0; nt < 8; nt++){
                int col = nt * 16 + t;
                float v = acc[nt][r] + bv[nt];
                if (MODE == 0) v = fmaxf(v, 0.f);
                OUTb[(size_t)row * H + col] = f2b(v);
            }
        }
    }
}

// ---------------- attention fold ----------------
__global__ __launch_bounds__(128) void k_qk(const float* __restrict__ ipW, const float* __restrict__ ipb,
                                            const float* __restrict__ query,
                                            float* __restrict__ qk, float* __restrict__ qkb){
    __shared__ float qs[H];
    int t = threadIdx.x;
    float a = ipb[t];
    for (int c = 0; c < H; c++) a += ipW[t * H + c] * query[c];
    qs[t] = a;
    __syncthreads();
    const float r32 = 0.17677669529663687f;
    #pragma unroll
    for (int h = 0; h < 4; h++){
        float v = 0.f;
        for (int d = 0; d < 32; d++) v += ipW[(H + h * 32 + d) * H + t] * qs[h * 32 + d];
        qk[h * H + t] = v * r32;
    }
    if (t < 4){
        float z = 0.f;
        for (int d = 0; d < 32; d++) z += ipb[H + t * 32 + d] * qs[t * 32 + d];
        qkb[t] = z * r32;
    }
}

// ---------------- parallel softmax pool ----------------
__global__ __launch_bounds__(256) void k_smax(const float* __restrict__ scores, const int* __restrict__ start,
                                              float* __restrict__ smax, int B){
    int idx = blockIdx.x * 4 + (threadIdx.x >> 6);
    if (idx >= B * 4) return;
    int b = idx >> 2, h = idx & 3, l = threadIdx.x & 63;
    int s0 = start[b], s1 = start[b + 1];
    float m = -1e30f;
    for (int n = s0 + l; n < s1; n += 64) m = fmaxf(m, scores[n * 4 + h]);
    #pragma unroll
    for (int s = 1; s < 64; s <<= 1) m = fmaxf(m, __shfl_xor(m, s, 64));
    if (l == 0) smax[idx] = m;
}

__global__ __launch_bounds__(128) void k_poolsum(const float* __restrict__ scores, const u16* __restrict__ Vb,
                                                 const int* __restrict__ start, const float* __restrict__ smax,
                                                 float* __restrict__ praw, float* __restrict__ den){
    int b = blockIdx.x / PPG, p = blockIdx.x % PPG;
    int c = threadIdx.x, h = c >> 5;
    int s0 = start[b], s1 = start[b + 1];
    float sm = smax[b * 4 + h];
    float acc = 0.f, se = 0.f;
    for (int n = s0 + p; n < s1; n += PPG){
        float e = expf(scores[n * 4 + h] - sm);
        acc += e * b2f(Vb[(size_t)n * H + c]);
        se += e;
    }
    atomicAdd(&praw[b * H + c], acc);
    if ((c & 31) == 0) atomicAdd(&den[b * 4 + h], se);
}

// ---------------- tail ----------------
__global__ __launch_bounds__(128) void k_tail(
    const float* __restrict__ praw, const float* __restrict__ den,
    const float* __restrict__ outW, const float* __restrict__ outb,
    const float* __restrict__ symfeat, const float* __restrict__ symW, const float* __restrict__ symb,
    const float* __restrict__ sfW, const float* __restrict__ sfb, const float* __restrict__ sfg, const float* __restrict__ sfbeta,
    const float* __restrict__ fusW, const float* __restrict__ fusb, const float* __restrict__ fusg, const float* __restrict__ fusbeta,
    const float* __restrict__ hW1, const float* __restrict__ hb1, const float* __restrict__ hW2, const float* __restrict__ hb2,
    float* __restrict__ dout, int B){
    int b = blockIdx.x, t = threadIdx.x;
    __shared__ float P[H], G[H], EMB[H], S[H], F[H], HHs[192], red[H], mm[2];
    float dh = den[b * 4 + (t >> 5)];
    P[t] = (dh > 0.f) ? praw[b * H + t] / dh : 0.f;
    __syncthreads();
    float a = outb[t];
    for (int c = 0; c < H; c++) a += P[c] * outW[t * H + c];
    G[t] = a;
    {
        int f = t >> 5;
        float e = symb[t];
        for (int i = 0; i < 16; i++) e += symfeat[b * 64 + f * 16 + i] * symW[t * 16 + i];
        EMB[t] = fmaxf(e, 0.f);
    }
    __syncthreads();
    float a2 = sfb[t];
    for (int c = 0; c < H; c++) a2 += EMB[c] * sfW[t * H + c];
    a2 = fmaxf(a2, 0.f);
    red[t] = a2; __syncthreads();
    for (int s = 64; s > 0; s >>= 1){ if (t < s) red[t] += red[t + s]; __syncthreads(); }
    if (t == 0) mm[0] = red[0];
    __syncthreads();
    red[t] = a2 * a2; __syncthreads();
    for (int s = 64; s > 0; s >>= 1){ if (t < s) red[t] += red[t + s]; __syncthreads(); }
    if (t == 0) mm[1] = red[0];
    __syncthreads();
    {
        float mean = mm[0] * (1.f / H), var = mm[1] * (1.f / H) - mean * mean;
        float rstd = rsqrtf(var + 1e-5f);
        S[t] = (a2 - mean) * rstd * sfg[t] + sfbeta[t];
    }
    __syncthreads();
    float fu = fusb[t];
    for (int c = 0; c < H; c++) fu += G[c] * fusW[t * 256 + c];
    for (int c = 0; c < H; c++) fu += S[c] * fusW[t * 256 + 128 + c];
    fu = fmaxf(fu, 0.f);
    red[t] = fu; __syncthreads();
    for (int s = 64; s > 0; s >>= 1){ if (t < s) red[t] += red[t + s]; __syncthreads(); }
    if (t == 0) mm[0] = red[0];
    __syncthreads();
    red[t] = fu * fu; __syncthreads();
    for (int s = 64; s > 0; s >>= 1){ if (t < s) red[t] += red[t + s]; __syncthreads(); }
    if (t == 0) mm[1] = red[0];
    __syncthreads();
    {
        float mean = mm[0] * (1.f / H), var = mm[1] * (1.f / H) - mean * mean;
        float rstd = rsqrtf(var + 1e-5f);
        F[t] = (fu - mean) * rstd * fusg[t] + fusbeta[t];
    }
    __syncthreads();
    for (int idx = t; idx < 192; idx += 128){
        float hv = hb1[idx];
        for (int c = 0; c < H; c++) hv += F[c] * hW1[idx * H + c];
        HHs[idx] = fmaxf(hv, 0.f);
    }
    __syncthreads();
    if (t < 3){
        float z = hb2[t];
        for (int o = 0; o < 64; o++) z += HHs[t * 64 + o] * hW2[t * 64 + o];
        dout[t * B + b] = 1.f / (1.f + expf(-z));
    }
}

extern "C" void kernel_launch(void* const* d_in, const int* in_sizes, int n_in,
                              void* d_out, int out_size, void* d_ws, size_t ws_size,
                              hipStream_t stream){
    const float* NF      = (const float*)d_in[0];
    const float* SYMF    = (const float*)d_in[1];
    const int*   EIDX    = (const int*)d_in[2];
    const int*   BATCH   = (const int*)d_in[3];
    const float* W_in    = (const float*)d_in[4];
    const float* b_in    = (const float*)d_in[5];
    const float* sWl     = (const float*)d_in[6];
    const float* sbl     = (const float*)d_in[7];
    const float* sWr     = (const float*)d_in[8];
    const float* lng     = (const float*)d_in[9];
    const float* lnb     = (const float*)d_in[10];
    const float* query   = (const float*)d_in[11];
    const float* ipW     = (const float*)d_in[12];
    const float* ipb     = (const float*)d_in[13];
    const float* outW    = (const float*)d_in[14];
    const float* outb    = (const float*)d_in[15];
    const float* symW    = (const float*)d_in[16];
    const float* symb    = (const float*)d_in[17];
    const float* sfW     = (const float*)d_in[18];
    const float* sfb     = (const float*)d_in[19];
    const float* sfg     = (const float*)d_in[20];
    const float* sfbeta  = (const float*)d_in[21];
    const float* fusW    = (const float*)d_in[22];
    const float* fusb    = (const float*)d_in[23];
    const float* fusg    = (const float*)d_in[24];
    const float* fusbeta = (const float*)d_in[25];
    const float* hW1     = (const float*)d_in[26];
    const float* hb1     = (const float*)d_in[27];
    const float* hW2     = (const float*)d_in[28];
    const float* hb2     = (const float*)d_in[29];

    const int N = in_sizes[0] / H;
    const int E = in_sizes[2] / 2;
    const int B = in_sizes[1] / 64;
    const int* esrc = EIDX;
    const int* edst = EIDX + E;
    const int NBK = (N + 255) >> BKSH;

    char* w = (char*)d_ws;
    auto alloc = [&](size_t bytes) -> char* {
        char* p = w; w += (bytes + 255) & ~(size_t)255; return p;
    };
    u16*   X0      = (u16*)alloc((size_t)N * H * 2);     // ping
    u16*   X1      = (u16*)alloc((size_t)N * H * 2);     // pong
    float* scores  = (float*)alloc((size_t)N * 4 * 4);
    unsigned* ebuf = (unsigned*)alloc((size_t)E * 4);
    char* zbase    = w;
    int* bcnt      = (int*)alloc((size_t)NBK * 4);
    float* praw    = (float*)alloc((size_t)B * H * 4);
    float* den     = (float*)alloc((size_t)B * 4 * 4);
    size_t zbytes  = (size_t)(w - zbase);
    int* boff      = (int*)alloc((size_t)(NBK + 1) * 4);
    int* bcur      = (int*)alloc((size_t)NBK * 4);
    int* offs      = (int*)alloc((size_t)(N + 1) * 4);
    float* invdeg  = (float*)alloc((size_t)N * 4);
    int* csr       = (int*)alloc((size_t)E * 4);
    int* start     = (int*)alloc((size_t)(B + 1) * 4);
    float* smax    = (float*)alloc((size_t)B * 4 * 4);
    float* qk      = (float*)alloc((size_t)4 * H * 4);
    float* qkb     = (float*)alloc(4 * 4);
    const int WSZ  = H * H;
    u16* Win = (u16*)alloc(WSZ * 2);
    u16* Wl  = (u16*)alloc(3 * WSZ * 2);
    u16* Wr  = (u16*)alloc(3 * WSZ * 2);
    u16* Wv  = (u16*)alloc(WSZ * 2);

    hipMemsetAsync(zbase, 0, zbytes, stream);

    const int cb = (E + CH - 1) / CH;
    k_bcnt<<<cb, 1024, 0, stream>>>(edst, bcnt, E, NBK);
    k_bscan<<<1, 64, 0, stream>>>(bcnt, boff, bcur, offs, NBK, N);
    k_bscatter<<<cb, 1024, 0, stream>>>(esrc, edst, ebuf, bcur, E, NBK);
    k_bfill<<<NBK, 256, 0, stream>>>(ebuf, boff, offs, csr, invdeg, N);
    k_start<<<(N + 255) / 256, 256, 0, stream>>>(BATCH, start, N, B);
    k_qk<<<1, 128, 0, stream>>>(ipW, ipb, query, qk, qkb);

    k_split<<<(WSZ + 255) / 256, 256, 0, stream>>>(W_in, Win, WSZ);
    k_split<<<(3 * WSZ + 255) / 256, 256, 0, stream>>>(sWl, Wl, 3 * WSZ);
    k_split<<<(3 * WSZ + 255) / 256, 256, 0, stream>>>(sWr, Wr, 3 * WSZ);
    k_split<<<(WSZ + 255) / 256, 256, 0, stream>>>(ipW + 2 * H * H, Wv, WSZ);

    const int gb = (N + 63) / 64;
    k_proj<0><<<gb, 256, 0, stream>>>(NF, Win, b_in, X0, N);
    // layer 0: X0 -> X1 ; layer 1: X1 -> X0 ; layer 2 (fused scores): X0 -> X1
    k_layer<false><<<gb, 512, 0, stream>>>(X0, X1, Wl + 0 * WSZ, Wr + 0 * WSZ,
                                           sbl + 0 * H, lng + 0 * H, lnb + 0 * H,
                                           offs, csr, invdeg, nullptr, nullptr, nullptr, N);
    k_layer<false><<<gb, 512, 0, stream>>>(X1, X0, Wl + 1 * WSZ, Wr + 1 * WSZ,
                                           sbl + 1 * H, lng + 1 * H, lnb + 1 * H,
                                           offs, csr, invdeg, nullptr, nullptr, nullptr, N);
    k_layer<true><<<gb, 512, 0, stream>>>(X0, X1, Wl + 2 * WSZ, Wr + 2 * WSZ,
                                          sbl + 2 * H, lng + 2 * H, lnb + 2 * H,
                                          offs, csr, invdeg, qk, qkb, scores, N);
    // V projection: X1 -> Vb (reuse X0)
    u16* Vb = X0;
    k_proj<2><<<gb, 256, 0, stream>>>(X1, Wv, ipb + 2 * H, Vb, N);
    k_smax<<<B, 256, 0, stream>>>(scores, start, smax, B);
    k_poolsum<<<B * PPG, 128, 0, stream>>>(scores, Vb, start, smax, praw, den);
    k_tail<<<B, 128, 0, stream>>>(praw, den, outW, outb, SYMF, symW, symb,
                                  sfW, sfb, sfg, sfbeta, fusW, fusb, fusg, fusbeta,
                                  hW1, hb1, hW2, hb2, (float*)d_out, B);
}